// Round 2
// baseline (43653.491 us; speedup 1.0000x reference)
//
#include <hip/hip_runtime.h>
#include <stdint.h>

// DecoderRNN: 2-layer GRU, H=512, B=64, T=1024, OUT=1, autoregressive scalar feedback.
// Persistent kernel: 256 WGs x 512 threads, 1 WG/CU (co-resident), 3 device barriers/step.
// WG w: bg=w>>7 -> batch rows [32*bg, 32*bg+32); ng=w&127 -> neurons [4*ng, 4*ng+4).
// Weights for the WG's neuron slice live in LDS (loaded once). Activations exchanged
// through d_ws with a hand-rolled epoch barrier (agent-scope atomics; poison 0xAA is
// negative as int so uninitialized slots can never satisfy "epoch >= e").

#define HH   512
#define TT   1024
#define NWG  256
#define NT   512
#define HPAD 516   // hbuf row stride (floats); 516*4B is 16B-aligned, breaks bank conflicts

struct __align__(16) Smem {
  float Wh0[12*HH];    // W_hh0 rows {g*512 + n0+nl}, layout [(g*4+nl)*512 + k]
  float Wi1[12*HH];    // W_ih1 rows, same layout
  float Wh1[12*HH];    // W_hh1 rows, same layout
  float Wo1[4*HH];     // W_o1 rows n0..n0+3
  float hbuf[32*HPAD]; // staged activation rows [bb][k], padded
  float gictx[12*32];  // ctx @ W_ih0[:, :512].T + b_ih0, for our 12 rows x 32 batch
  float gi1s[12*32];   // per-step gi1 stash between P2a and P2b
  float wcol[12];      // W_ih0[:, 512] (the `prev` column)
  float bhh0[12];
  float bih1[12];
  float bhh1[12];
  float bo1v[4];
  float wo2v[4];
  float prevS[32];
  float outred[32];
  float bo2S;
};

__device__ __forceinline__ float sigm(float x){ return 1.f/(1.f + expf(-x)); }

// Epoch barrier across all NWG workgroups. slots[w] / *epoch are ints in d_ws
// (0xAAAAAAAA poison is negative -> safe). Release on arrival publishes this WG's
// global writes (L2 writeback); one acquire fence after observing the epoch imports them.
__device__ __forceinline__ void gbar(int* slots, int* epoch, int w, int tid, int e){
  __syncthreads();
  if (tid == 0)
    __hip_atomic_store(&slots[w], e, __ATOMIC_RELEASE, __HIP_MEMORY_SCOPE_AGENT);
  if (w == 0 && tid < 64){
    for(;;){
      int m0 = __hip_atomic_load(&slots[tid*4+0], __ATOMIC_RELAXED, __HIP_MEMORY_SCOPE_AGENT);
      int m1 = __hip_atomic_load(&slots[tid*4+1], __ATOMIC_RELAXED, __HIP_MEMORY_SCOPE_AGENT);
      int m2 = __hip_atomic_load(&slots[tid*4+2], __ATOMIC_RELAXED, __HIP_MEMORY_SCOPE_AGENT);
      int m3 = __hip_atomic_load(&slots[tid*4+3], __ATOMIC_RELAXED, __HIP_MEMORY_SCOPE_AGENT);
      int mn = min(min(m0,m1), min(m2,m3));
      if (__all(mn >= e)) break;
      __builtin_amdgcn_s_sleep(2);
    }
    if (tid == 0)
      __hip_atomic_store(epoch, e, __ATOMIC_RELEASE, __HIP_MEMORY_SCOPE_AGENT);
  }
  if (tid == 0){
    while (__hip_atomic_load(epoch, __ATOMIC_RELAXED, __HIP_MEMORY_SCOPE_AGENT) < e)
      __builtin_amdgcn_s_sleep(2);
    __builtin_amdgcn_fence(__ATOMIC_ACQUIRE, "agent");
  }
  __syncthreads();
}

extern "C" __global__ void __launch_bounds__(NT, 1)
decoder_rnn(const float* __restrict__ ctx,   // [64][512]
            const float* __restrict__ Wih0,  // [1536][513]  (!! row stride 513)
            const float* __restrict__ Whh0,  // [1536][512]
            const float* __restrict__ bih0,
            const float* __restrict__ bhh0g,
            const float* __restrict__ Wih1,  // [1536][512]
            const float* __restrict__ Whh1,  // [1536][512]
            const float* __restrict__ bih1g,
            const float* __restrict__ bhh1g,
            const float* __restrict__ Wo1,   // [512][512]
            const float* __restrict__ bo1g,
            const float* __restrict__ Wo2,   // [512]
            const float* __restrict__ bo2g,
            float* __restrict__ out,         // [65536 outputs][65536 h_i]
            float* __restrict__ ws)
{
  extern __shared__ char smem_raw[];
  Smem& S = *reinterpret_cast<Smem*>(smem_raw);
  const int tid = threadIdx.x;
  const int w   = blockIdx.x;
  const int bg  = w >> 7, ng = w & 127;
  const int b0  = bg * 32, n0 = ng * 4;

  float* h0A   = ws;
  float* h0B   = ws + 32768;
  float* h1A   = ws + 65536;
  float* h1B   = ws + 98304;
  float* outac = ws + 131072;            // [1024][64] raw (pre-relu, pre-bias) sums
  int*   slots = (int*)(ws + 196608);
  int*   epoch = slots + NWG;

  // ---------------- init (all before first barrier) ----------------
  if (tid < 128){ h0A[w*128 + tid] = 0.f; h1A[w*128 + tid] = 0.f; }
  if (tid < 256) outac[w*256 + tid] = 0.f;

  for (int i = tid; i < 12*HH; i += NT){
    int rl = i >> 9, k = i & 511;
    int g = rl >> 2, nli = rl & 3;
    int grow = g*HH + n0 + nli;
    S.Wh0[i] = Whh0[(size_t)grow*HH + k];
    S.Wi1[i] = Wih1[(size_t)grow*HH + k];
    S.Wh1[i] = Whh1[(size_t)grow*HH + k];
  }
  for (int i = tid; i < 4*HH; i += NT){
    int nli = i >> 9, k = i & 511;
    S.Wo1[i] = Wo1[(size_t)(n0+nli)*HH + k];
  }
  if (tid < 12){
    int g = tid >> 2, nli = tid & 3;
    int grow = g*HH + n0 + nli;
    S.wcol[tid] = Wih0[(size_t)grow*513 + 512];
    S.bhh0[tid] = bhh0g[grow];
    S.bih1[tid] = bih1g[grow];
    S.bhh1[tid] = bhh1g[grow];
  }
  if (tid < 4){ S.bo1v[tid] = bo1g[n0+tid]; S.wo2v[tid] = Wo2[n0+tid]; }
  if (tid == 0) S.bo2S = bo2g[0];

  // gi_ctx = ctx @ W_ih0[:, :512].T + b_ih0 for our 12 rows x 32 batch (one-time)
  if (tid < 384){
    int rl = tid >> 5, bb = tid & 31;
    int g = rl >> 2, nli = rl & 3;
    int grow = g*HH + n0 + nli;
    const float* wr = Wih0 + (size_t)grow * 513;
    const float* cx = ctx  + (size_t)(b0+bb) * HH;
    float s = bih0[grow];
    for (int k = 0; k < HH; k += 4)
      s += wr[k]*cx[k] + wr[k+1]*cx[k+1] + wr[k+2]*cx[k+2] + wr[k+3]*cx[k+3];
    S.gictx[rl*32 + bb] = s;
  }

  gbar(slots, epoch, w, tid, 1);

  // per-thread dot mapping: 128 items (nl in [0,4), bb in [0,32)) x 4 K-parts
  const int p  = tid & 3;
  const int it = tid >> 2;
  const int bb = it & 31;
  const int nl = it >> 5;
  float4* hb4 = (float4*)(S.hbuf) + bb * (HPAD/4);

  // stage 32 rows x 512 floats from global into S.hbuf (padded)
  auto stage = [&](const float* src){
    const float4* s4 = (const float4*)(src + (size_t)b0 * HH);
    #pragma unroll
    for (int i = tid; i < 4096; i += NT){
      int r = i >> 7, c = i & 127;
      *((float4*)(S.hbuf + r*HPAD) + c) = s4[r*128 + c];
    }
  };

  // 3 gate-row dots of length 512 vs S.hbuf row bb; K split 4-way across p,
  // interleaved (k = 4p + 16m) so h-reads stay ~2-way bank conflict free.
  auto dot3 = [&](const float* Wbase, float& a0, float& a1, float& a2){
    const float4* w40 = (const float4*)Wbase + nl*128;
    const float4* w41 = w40 + 512;
    const float4* w42 = w41 + 512;
    float s0 = 0.f, s1 = 0.f, s2 = 0.f;
    #pragma unroll 8
    for (int m = 0; m < 32; ++m){
      int idx = p + 4*m;
      float4 h4 = hb4[idx];
      float4 q0 = w40[idx], q1 = w41[idx], q2 = w42[idx];
      s0 += h4.x*q0.x + h4.y*q0.y + h4.z*q0.z + h4.w*q0.w;
      s1 += h4.x*q1.x + h4.y*q1.y + h4.z*q1.z + h4.w*q1.w;
      s2 += h4.x*q2.x + h4.y*q2.y + h4.z*q2.z + h4.w*q2.w;
    }
    s0 += __shfl_xor(s0,1); s0 += __shfl_xor(s0,2);
    s1 += __shfl_xor(s1,1); s1 += __shfl_xor(s1,2);
    s2 += __shfl_xor(s2,1); s2 += __shfl_xor(s2,2);
    a0 = s0; a1 = s1; a2 = s2;
  };

  for (int t = 0; t < TT; ++t){
    const float* h0c = (t & 1) ? h0B : h0A;
    float*       h0n = (t & 1) ? h0A : h0B;
    const float* h1c = (t & 1) ? h1B : h1A;
    float*       h1n = (t & 1) ? h1A : h1B;

    // ---- P1: prev recovery, layer-0 GRU ----
    if (tid < 32){
      float pv = 0.f;
      if (t > 0) pv = fmaxf(outac[(size_t)(t-1)*64 + b0 + tid] + S.bo2S, 0.f);
      S.prevS[tid] = pv;
      if (ng == 0 && t > 0) out[(size_t)(b0+tid)*TT + (t-1)] = pv;  // y[t-1]
    }
    stage(h0c);
    __syncthreads();
    {
      float a0, a1, a2;
      dot3(S.Wh0, a0, a1, a2);
      if (p == 0){
        float pv  = S.prevS[bb];
        float ir  = S.gictx[(0*4+nl)*32+bb] + pv*S.wcol[0*4+nl];
        float iz  = S.gictx[(1*4+nl)*32+bb] + pv*S.wcol[1*4+nl];
        float inn = S.gictx[(2*4+nl)*32+bb] + pv*S.wcol[2*4+nl];
        float hr = a0 + S.bhh0[0*4+nl];
        float hz = a1 + S.bhh0[1*4+nl];
        float hn = a2 + S.bhh0[2*4+nl];
        float r  = sigm(ir + hr);
        float z  = sigm(iz + hz);
        float nn = tanhf(inn + r*hn);
        float h0old = S.hbuf[bb*HPAD + (n0+nl)];
        h0n[(size_t)(b0+bb)*HH + n0 + nl] = (1.f - z)*nn + z*h0old;
      }
    }
    gbar(slots, epoch, w, tid, 3*t + 2);

    // ---- P2a: gi1 = h0n @ W_ih1.T ----
    stage(h0n);
    __syncthreads();
    {
      float a0, a1, a2;
      dot3(S.Wi1, a0, a1, a2);
      if (p == 0){
        S.gi1s[(0*4+nl)*32+bb] = a0 + S.bih1[0*4+nl];
        S.gi1s[(1*4+nl)*32+bb] = a1 + S.bih1[1*4+nl];
        S.gi1s[(2*4+nl)*32+bb] = a2 + S.bih1[2*4+nl];
      }
    }
    __syncthreads();
    // ---- P2b: gh1 = h1 @ W_hh1.T, layer-1 GRU ----
    stage(h1c);
    __syncthreads();
    {
      float a0, a1, a2;
      dot3(S.Wh1, a0, a1, a2);
      if (p == 0){
        float i1r = S.gi1s[(0*4+nl)*32+bb];
        float i1z = S.gi1s[(1*4+nl)*32+bb];
        float i1n = S.gi1s[(2*4+nl)*32+bb];
        float r1 = sigm(i1r + a0 + S.bhh1[0*4+nl]);
        float z1 = sigm(i1z + a1 + S.bhh1[1*4+nl]);
        float n1 = tanhf(i1n + r1*(a2 + S.bhh1[2*4+nl]));
        float h1old = S.hbuf[bb*HPAD + (n0+nl)];
        h1n[(size_t)(b0+bb)*HH + n0 + nl] = (1.f - z1)*n1 + z1*h1old;
      }
    }
    gbar(slots, epoch, w, tid, 3*t + 3);

    // ---- P3: y = relu(h1n @ W_o1.T + b_o1); partial out = wo2 . y ----
    if (tid < 32) S.outred[tid] = 0.f;
    stage(h1n);
    __syncthreads();
    {
      const float4* w4 = (const float4*)(S.Wo1) + nl*128;
      float s0 = 0.f;
      #pragma unroll 8
      for (int m = 0; m < 32; ++m){
        int idx = p + 4*m;
        float4 h4 = hb4[idx];
        float4 q0 = w4[idx];
        s0 += h4.x*q0.x + h4.y*q0.y + h4.z*q0.z + h4.w*q0.w;
      }
      s0 += __shfl_xor(s0,1); s0 += __shfl_xor(s0,2);
      if (p == 0){
        float y = fmaxf(s0 + S.bo1v[nl], 0.f);
        atomicAdd(&S.outred[bb], S.wo2v[nl]*y);
      }
    }
    __syncthreads();
    if (tid < 32)
      atomicAdd(&outac[(size_t)t*64 + b0 + tid], S.outred[tid]);
    gbar(slots, epoch, w, tid, 3*t + 4);
  }

  // ---- finale: y[1023] and final hidden states ----
  if (tid < 32 && ng == 0){
    float fv = fmaxf(outac[(size_t)1023*64 + b0 + tid] + S.bo2S, 0.f);
    out[(size_t)(b0+tid)*TT + 1023] = fv;
  }
  {
    // after t=1023 (odd), final states live in h0A / h1A
    int g = w*NT + tid;
    if (g < 32768)      out[65536 + g] = h0A[g];
    else if (g < 65536) out[65536 + g] = h1A[g - 32768];
  }
}

extern "C" void kernel_launch(void* const* d_in, const int* in_sizes, int n_in,
                              void* d_out, int out_size, void* d_ws, size_t ws_size,
                              hipStream_t stream){
  const float* ctx   = (const float*)d_in[0];
  // d_in[1] = expected_output (only its length matters; T fixed at 1024)
  const float* Wih0  = (const float*)d_in[2];
  const float* Whh0  = (const float*)d_in[3];
  const float* bih0  = (const float*)d_in[4];
  const float* bhh0  = (const float*)d_in[5];
  const float* Wih1  = (const float*)d_in[6];
  const float* Whh1  = (const float*)d_in[7];
  const float* bih1  = (const float*)d_in[8];
  const float* bhh1  = (const float*)d_in[9];
  const float* Wo1   = (const float*)d_in[10];
  const float* bo1   = (const float*)d_in[11];
  const float* Wo2   = (const float*)d_in[12];
  const float* bo2   = (const float*)d_in[13];
  // d_in[14] = force (always 0, ignored by reference)

  (void)in_sizes; (void)n_in; (void)out_size; (void)ws_size;

  (void)hipFuncSetAttribute((const void*)decoder_rnn,
                            hipFuncAttributeMaxDynamicSharedMemorySize,
                            (int)sizeof(Smem));

  decoder_rnn<<<NWG, NT, sizeof(Smem), stream>>>(
      ctx, Wih0, Whh0, bih0, bhh0, Wih1, Whh1, bih1, bhh1,
      Wo1, bo1, Wo2, bo2, (float*)d_out, (float*)d_ws);
}